// Round 6
// baseline (264.180 us; speedup 1.0000x reference)
//
#include <hip/hip_runtime.h>
#include <hip/hip_bf16.h>

// ---------------------------------------------------------------------------
// R20: enc = R14/R19 verbatim (closed at 94.6us: per-wave issue 570cy/step,
// VALUBusy 51% = 4.125 waves x 12.5% duty additive; stagger/ILP/pipeline/
// trans-algebra all falsified R15-R18). Remaining lever: the R1-vintage
// DECODER runs at 2 waves/SIMD (256 blk x 512 thr) with the same latency
// profile (wall 2000cy/step vs ~540cy/wave issue). Enc's lesson: max TLP at
// min per-wave grain wins this regime. dec20: split each row-dot K=128 into
// two 64-halves across thread PAIRS (tid&1), 1024 thr/block -> 4 waves/SIMD,
// per-wave issue halved, total issue and weight traffic unchanged (still 256
// blocks), one __shfl_xor(psum,1) per row to combine. Same fp32 ops, summation
// order differs negligibly (4acc x 64 + pair-add). Update/epilogue phases
// unchanged (tid<256 / wv<4).
// Predict: dec ~25 -> ~17-19us, total 246.6 -> ~239-241us, enc rows identical,
// absmax 2.44e-4. Neutral => dec also plateau'd -> declare roofline. >5us
// regression => revert dec19.
// ---------------------------------------------------------------------------

typedef __attribute__((ext_vector_type(8))) short bf16x8;
typedef __attribute__((ext_vector_type(4))) float f32x4;
typedef unsigned int uint;
typedef unsigned short ushort_t;

#define LOG2E  1.4426950408889634f
#define LOG2E2 2.8853900817779268f

__device__ __forceinline__ float rcp_fast(float x) { return __builtin_amdgcn_rcpf(x); }
__device__ __forceinline__ float exp2_fast(float x) { return __builtin_amdgcn_exp2f(x); }
__device__ __forceinline__ float sigf(float x) { return rcp_fast(1.0f + __expf(-x)); }
__device__ __forceinline__ float tanh_fast(float x) {
    x = fminf(fmaxf(x, -15.0f), 15.0f);
    float e = __expf(2.0f * x);
    return (e - 1.0f) * rcp_fast(e + 1.0f);
}
__device__ __forceinline__ ushort_t bf_hi(float f) {
    union { float f; uint u; } v; v.f = f;
    return (ushort_t)(v.u >> 16);
}
__device__ __forceinline__ ushort_t bf_rtn(float f) {
    union { float f; uint u; } v; v.f = f;
    return (ushort_t)((v.u + 0x7FFFu + ((v.u >> 16) & 1u)) >> 16);
}
__device__ __forceinline__ float bf_f(ushort_t h) {
    union { float f; uint u; } v; v.u = ((uint)h) << 16;
    return v.f;
}

// Pre-scaled (log2e; g by 2log2e) cell update, 5 exp2 + 2 rcp:
//   A=1+e^-f, B=1+e^-i, C=1+e^{2g};  c' = [c*B*C + (C-2)*A] * rcp(A*B*C)
__device__ __forceinline__ float cell_update_p(float xi, float xf, float xg,
                                               float xo, float& c) {
    float pi = exp2_fast(-xi);
    float pf = exp2_fast(-xf);
    float po = exp2_fast(-xo);
    float pg = exp2_fast(fminf(xg, 120.0f));
    float A = 1.0f + pf;
    float B = 1.0f + pi;
    float C = 1.0f + pg;
    float BC = B * C;
    float R  = rcp_fast(A * BC);
    float num = __builtin_fmaf(c, BC, (C - 2.0f) * A);
    float cc = num * R;
    c = cc;
    float e2 = exp2_fast(fminf(cc * LOG2E2, 120.0f));
    return (e2 - 1.0f) * rcp_fast((1.0f + po) * (e2 + 1.0f));
}

// ======================= encoder: H=64, T=50 ==============================
// 16 seqs/block; 4 waves; wave wv owns units 16wv..16wv+15 for all 4 gates.
// hb row: 32 dwords = 64 bf16 h (RTN), pad to 36 dwords.
#define HS 36

__global__ __launch_bounds__(256, 4) void enc20_kernel(
    const float* __restrict__ ax, const float* __restrict__ nx,
    const float* __restrict__ a_wih, const float* __restrict__ a_whh,
    const float* __restrict__ a_bih, const float* __restrict__ a_bhh,
    const float* __restrict__ n_wih, const float* __restrict__ n_whh,
    const float* __restrict__ n_bih, const float* __restrict__ n_bhh,
    float* __restrict__ nh_out, float* __restrict__ ah_out)
{
    const int tid = threadIdx.x, blk = blockIdx.x;
    const bool agent = (blk >= 1024);
    const int seq0 = (agent ? (blk - 1024) : blk) * 16;
    const float* __restrict__ x   = agent ? ax : nx;
    const float* __restrict__ wih = agent ? a_wih : n_wih;
    const float* __restrict__ whh = agent ? a_whh : n_whh;
    const float* __restrict__ bih = agent ? a_bih : n_bih;
    const float* __restrict__ bhh = agent ? a_bhh : n_bhh;
    float* __restrict__ hout = agent ? ah_out : nh_out;

    const int lane = tid & 63, wv = tid >> 6;
    const int col = lane & 15, quad = lane >> 4;

    __shared__ __attribute__((aligned(16))) uint hb[2][16][HS];
    __shared__ __attribute__((aligned(16))) ushort_t xb[50][16][8];

    // A fragments: Whh rows, single RTN bf16, pre-scaled by log2e (2log2e for
    // the g gate). A row = g*64+16wv+col.
    bf16x8 Aw[4][2];
    #pragma unroll
    for (int g = 0; g < 4; ++g) {
        const float sc = (g == 2) ? LOG2E2 : LOG2E;
        #pragma unroll
        for (int kt = 0; kt < 2; ++kt) {
            const float* p = whh + (size_t)(g * 64 + 16 * wv + col) * 64 + kt * 32 + quad * 8;
            float4 v0 = *(const float4*)p;
            float4 v1 = *(const float4*)(p + 4);
            float vv[8] = { v0.x, v0.y, v0.z, v0.w, v1.x, v1.y, v1.z, v1.w };
            bf16x8 h8;
            #pragma unroll
            for (int j = 0; j < 8; ++j) h8[j] = (short)bf_rtn(vv[j] * sc);
            Aw[g][kt] = h8;
        }
    }

    // 3rd-tile A fragments (x + bias, pre-scaled): nonzero only on quad 0.
    bf16x8 Ax[4];
    #pragma unroll
    for (int g = 0; g < 4; ++g) {
        const float sc = (g == 2) ? LOG2E2 : LOG2E;
        bf16x8 a;
        #pragma unroll
        for (int j = 0; j < 8; ++j) a[j] = 0;
        if (quad == 0) {
            const int row = g * 64 + 16 * wv + col;
            float w0 = wih[2 * row] * sc, w1 = wih[2 * row + 1] * sc;
            float b  = (bih[row] + bhh[row]) * sc;
            ushort_t w0h = bf_hi(w0), w1h = bf_hi(w1);
            ushort_t bh  = bf_hi(b);
            a[0] = (short)w0h;
            a[1] = (short)w1h;
            a[2] = (short)bf_hi(w0 - bf_f(w0h));
            a[3] = (short)bf_hi(w1 - bf_f(w1h));
            a[4] = (short)w0h;
            a[5] = (short)w1h;
            a[6] = (short)bh;
            a[7] = (short)bf_hi(b - bf_f(bh));
        }
        Ax[g] = a;
    }

    for (int idx = tid; idx < 50 * 16; idx += 256) {
        const int t = idx >> 4, s = idx & 15;
        const float* xp = x + (size_t)(seq0 + s) * 100 + 2 * t;
        float x0 = xp[0], x1 = xp[1];
        ushort_t h0 = bf_hi(x0), h1 = bf_hi(x1);
        ushort_t* e = &xb[t][s][0];
        e[0] = h0; e[1] = h1;
        e[2] = h0; e[3] = h1;
        e[4] = bf_hi(x0 - bf_f(h0));
        e[5] = bf_hi(x1 - bf_f(h1));
        e[6] = 0x3F80; e[7] = 0x3F80;
    }
    for (int i = tid; i < 16 * HS; i += 256) (&hb[0][0][0])[i] = 0u;
    __syncthreads();

    float c[4] = {0.f, 0.f, 0.f, 0.f};
    float hv[4];
    bf16x8 Bx = *(const bf16x8*)&xb[0][col][0];   // prefetched x-tile, t=0

    for (int t = 0; t < 50; ++t) {
        const int cur = t & 1, nxt = cur ^ 1;

        const f32x4 z4 = {0.f, 0.f, 0.f, 0.f};
        f32x4 acc[4];
        #pragma unroll
        for (int g = 0; g < 4; ++g)
            acc[g] = __builtin_amdgcn_mfma_f32_16x16x32_bf16(Ax[g], Bx, z4, 0, 0, 0);

        // Whh @ h: 1 MFMA per gate per kt
        #pragma unroll
        for (int kt = 0; kt < 2; ++kt) {
            bf16x8 Bhi = *(const bf16x8*)&hb[cur][col][kt * 16 + quad * 4];
            #pragma unroll
            for (int g = 0; g < 4; ++g)
                acc[g] = __builtin_amdgcn_mfma_f32_16x16x32_bf16(Aw[g][kt], Bhi, acc[g], 0, 0, 0);
        }

        // cell update: lane owns seq=col, units 16wv + 4quad + r
        #pragma unroll
        for (int r = 0; r < 4; ++r)
            hv[r] = cell_update_p(acc[0][r], acc[1][r], acc[2][r], acc[3][r], c[r]);

        // pack h (packed RTN cvt) -> LDS
        {
            __hip_bfloat162 p01 = __float22bfloat162_rn(make_float2(hv[0], hv[1]));
            __hip_bfloat162 p23 = __float22bfloat162_rn(make_float2(hv[2], hv[3]));
            uint2 hi2;
            union { __hip_bfloat162 b; uint u; } c0, c1;
            c0.b = p01; c1.b = p23;
            hi2.x = c0.u;
            hi2.y = c1.u;
            const int di = 8 * wv + 2 * quad;
            *(uint2*)&hb[nxt][col][di] = hi2;
        }
        // prefetch next x-tile BEFORE the barrier (xb is read-only: safe)
        if (t < 49) Bx = *(const bf16x8*)&xb[t + 1][col][0];
        __syncthreads();
    }

    // peeled final store (hv holds t=49 values)
    {
        float4 o4 = make_float4(hv[0], hv[1], hv[2], hv[3]);
        *(float4*)(hout + (size_t)(seq0 + col) * 64 + 16 * wv + 4 * quad) = o4;
    }
}

// ============ decoder R20: split-K pairs, 1024 thr, 4 waves/SIMD ===========
// Thread pair (rp = tid>>1, half = tid&1): row r = (rp&3)*128 + (rp>>2),
// K-half = cols half*64..half*64+63. Combine via __shfl_xor(psum,1).
// Update (tid<256) and epilogue (wv<4) phases identical to dec19.
__global__ __launch_bounds__(1024) void dec20_kernel(
    const float* __restrict__ ah, const float* __restrict__ nh,
    const float* __restrict__ d_wih, const float* __restrict__ d_whh,
    const float* __restrict__ d_bih, const float* __restrict__ d_bhh,
    const float* __restrict__ e_w, const float* __restrict__ e_b,
    float* __restrict__ out)
{
    const int tid = threadIdx.x;
    const int blk = blockIdx.x;

    const int rp   = tid >> 1;      // 0..511 packed row index (tt = rp&3)
    const int half = tid & 1;       // K-half
    const int tt = rp & 3;
    const int u  = rp >> 2;
    const int r  = tt * 128 + u;

    float w[64];
    #pragma unroll
    for (int k = 0; k < 64; k += 4) {
        float4 aa = *(const float4*)(d_wih + r * 128 + half * 64 + k);
        float4 bb = *(const float4*)(d_whh + r * 128 + half * 64 + k);
        w[k]   = aa.x + bb.x;
        w[k+1] = aa.y + bb.y;
        w[k+2] = aa.z + bb.z;
        w[k+3] = aa.w + bb.w;
    }
    const float bias = d_bih[r] + d_bhh[r];   // added by half==0 only

    __shared__ float hs[2][128];
    __shared__ float cs[2][128];
    __shared__ float gs[2][512];
    __shared__ float ews[2][128];
    __shared__ float ebs[2];

    if (tid < 256) {
        const int s = tid >> 7, j = tid & 127;
        const int gseq = blk * 2 + s;
        float v;
        if (j < 64) {
            v = ah[(size_t)gseq * 64 + j];
        } else {
            float acc = 0.0f;
            for (int n = 0; n < 32; ++n)
                acc += nh[(size_t)(gseq * 32 + n) * 64 + (j - 64)];
            v = acc * (1.0f / 32.0f);
        }
        hs[s][j] = v;
        cs[s][j] = 0.0f;
        ews[s][j] = e_w[tid];
    }
    if (tid < 2) ebs[tid] = e_b[tid];
    __syncthreads();

    for (int t = 0; t < 30; ++t) {
        #pragma unroll
        for (int s = 0; s < 2; ++s) {
            const float4* hp = (const float4*)(&hs[s][half * 64]);
            float a0 = 0.f, a1 = 0.f, a2 = 0.f, a3 = 0.f;
            #pragma unroll
            for (int k = 0; k < 16; ++k) {
                float4 h4 = hp[k];
                a0 = __builtin_fmaf(w[4*k+0], h4.x, a0);
                a1 = __builtin_fmaf(w[4*k+1], h4.y, a1);
                a2 = __builtin_fmaf(w[4*k+2], h4.z, a2);
                a3 = __builtin_fmaf(w[4*k+3], h4.w, a3);
            }
            float psum = (a0 + a1) + (a2 + a3);
            psum += __shfl_xor(psum, 1);
            if (half == 0) gs[s][rp] = bias + psum;
        }
        __syncthreads();
        if (tid < 256) {
            const int s = tid >> 7, j = tid & 127;
            float4 g4 = *(const float4*)(&gs[s][4 * j]);
            float ig = sigf(g4.x), fg = sigf(g4.y);
            float gg = tanh_fast(g4.z), og = sigf(g4.w);
            float cc = fg * cs[s][j] + ig * gg;
            cs[s][j] = cc;
            hs[s][j] = og * tanh_fast(cc);
        }
        __syncthreads();
        {
            const int wv = tid >> 6, l = tid & 63;
            if (wv < 4) {
                const int s = wv >> 1, o = wv & 1;
                float p = hs[s][l] * ews[o][l] + hs[s][64 + l] * ews[o][64 + l];
                #pragma unroll
                for (int off = 32; off > 0; off >>= 1) p += __shfl_down(p, off);
                if (l == 0) out[((size_t)(blk * 2 + s) * 30 + t) * 2 + o] = p + ebs[o];
            }
        }
    }
}

extern "C" void kernel_launch(void* const* d_in, const int* in_sizes, int n_in,
                              void* d_out, int out_size, void* d_ws, size_t ws_size,
                              hipStream_t stream)
{
    const float* agent_traj = (const float*)d_in[0];
    const float* neigh_traj = (const float*)d_in[1];
    const float* a_wih = (const float*)d_in[2];
    const float* a_whh = (const float*)d_in[3];
    const float* a_bih = (const float*)d_in[4];
    const float* a_bhh = (const float*)d_in[5];
    const float* n_wih = (const float*)d_in[6];
    const float* n_whh = (const float*)d_in[7];
    const float* n_bih = (const float*)d_in[8];
    const float* n_bhh = (const float*)d_in[9];
    const float* d_wih = (const float*)d_in[10];
    const float* d_whh = (const float*)d_in[11];
    const float* d_bih = (const float*)d_in[12];
    const float* d_bhh = (const float*)d_in[13];
    const float* e_w   = (const float*)d_in[14];
    const float* e_b   = (const float*)d_in[15];
    float* out = (float*)d_out;

    float* nh_ws = (float*)d_ws;            // 16384*64 fp32
    float* ah_ws = nh_ws + 16384 * 64;      // 512*64 fp32

    enc20_kernel<<<dim3(1024 + 32), dim3(256), 0, stream>>>(
        agent_traj, neigh_traj,
        a_wih, a_whh, a_bih, a_bhh,
        n_wih, n_whh, n_bih, n_bhh,
        nh_ws, ah_ws);

    dec20_kernel<<<dim3(256), dim3(1024), 0, stream>>>(
        ah_ws, nh_ws, d_wih, d_whh, d_bih, d_bhh, e_w, e_b, out);
}

// Round 7
// 257.839 us; speedup vs baseline: 1.0246x; 1.0246x over previous
//
#include <hip/hip_runtime.h>
#include <hip/hip_bf16.h>

// ---------------------------------------------------------------------------
// R21: decoder rebuilt as an encoder-clone (MFMA recurrence).
// R20 post-mortem: dec20 at 104.7us exposed that dec19 was ~87us (not ~25);
// harness overhead is ~65us (not ~130). The decoder was an unoptimized
// co-equal component: per step every thread did 64 broadcast ds_read_b128 +
// 256 scalar FMAs with 3/4 of lanes idle in update/epilogue and 3 barriers.
// dec21: 32 blocks x 512 thr, 16 seqs/block; W = (d_wih + d_whh) folded once
// (both multiply h!), bf16 RTN + log2e prescale (enc's validated recipe);
// wave wv owns j in [16wv,16wv+16) for all 4 gates -> 16 MFMA + 4 updates/
// lane/step (enc's exact shape, kt=4 for K=128). h: bf16 in LDS for the
// recurrence + fp32 copy for the pred epilogue (output precision). Pred on
// wave 7 post-barrier, overlapped with next step's MFMAs. 1 barrier/step.
// Predict: dec ~87 -> ~15-25us, total -> ~180-200us; enc top-5 rows
// unchanged; absmax 2.4e-4 -> <=6e-4 (dec recurrence now bf16 like enc).
// Fallback if absmax fails or total >= 250: revert dec19.
// enc21 = enc19/R14 verbatim (closed at 94.6us, R15-R18 falsification arc).
// ---------------------------------------------------------------------------

typedef __attribute__((ext_vector_type(8))) short bf16x8;
typedef __attribute__((ext_vector_type(4))) float f32x4;
typedef unsigned int uint;
typedef unsigned short ushort_t;

#define LOG2E  1.4426950408889634f
#define LOG2E2 2.8853900817779268f

__device__ __forceinline__ float rcp_fast(float x) { return __builtin_amdgcn_rcpf(x); }
__device__ __forceinline__ float exp2_fast(float x) { return __builtin_amdgcn_exp2f(x); }
__device__ __forceinline__ ushort_t bf_hi(float f) {
    union { float f; uint u; } v; v.f = f;
    return (ushort_t)(v.u >> 16);
}
__device__ __forceinline__ ushort_t bf_rtn(float f) {
    union { float f; uint u; } v; v.f = f;
    return (ushort_t)((v.u + 0x7FFFu + ((v.u >> 16) & 1u)) >> 16);
}
__device__ __forceinline__ float bf_f(ushort_t h) {
    union { float f; uint u; } v; v.u = ((uint)h) << 16;
    return v.f;
}

// Pre-scaled (log2e; g by 2log2e) cell update, 5 exp2 + 2 rcp:
//   A=1+e^-f, B=1+e^-i, C=1+e^{2g};  c' = [c*B*C + (C-2)*A] * rcp(A*B*C)
__device__ __forceinline__ float cell_update_p(float xi, float xf, float xg,
                                               float xo, float& c) {
    float pi = exp2_fast(-xi);
    float pf = exp2_fast(-xf);
    float po = exp2_fast(-xo);
    float pg = exp2_fast(fminf(xg, 120.0f));
    float A = 1.0f + pf;
    float B = 1.0f + pi;
    float C = 1.0f + pg;
    float BC = B * C;
    float R  = rcp_fast(A * BC);
    float num = __builtin_fmaf(c, BC, (C - 2.0f) * A);
    float cc = num * R;
    c = cc;
    float e2 = exp2_fast(fminf(cc * LOG2E2, 120.0f));
    return (e2 - 1.0f) * rcp_fast((1.0f + po) * (e2 + 1.0f));
}

// ======================= encoder: H=64, T=50 ==============================
// 16 seqs/block; 4 waves; wave wv owns units 16wv..16wv+15 for all 4 gates.
// hb row: 32 dwords = 64 bf16 h (RTN), pad to 36 dwords.
#define HS 36

__global__ __launch_bounds__(256, 4) void enc21_kernel(
    const float* __restrict__ ax, const float* __restrict__ nx,
    const float* __restrict__ a_wih, const float* __restrict__ a_whh,
    const float* __restrict__ a_bih, const float* __restrict__ a_bhh,
    const float* __restrict__ n_wih, const float* __restrict__ n_whh,
    const float* __restrict__ n_bih, const float* __restrict__ n_bhh,
    float* __restrict__ nh_out, float* __restrict__ ah_out)
{
    const int tid = threadIdx.x, blk = blockIdx.x;
    const bool agent = (blk >= 1024);
    const int seq0 = (agent ? (blk - 1024) : blk) * 16;
    const float* __restrict__ x   = agent ? ax : nx;
    const float* __restrict__ wih = agent ? a_wih : n_wih;
    const float* __restrict__ whh = agent ? a_whh : n_whh;
    const float* __restrict__ bih = agent ? a_bih : n_bih;
    const float* __restrict__ bhh = agent ? a_bhh : n_bhh;
    float* __restrict__ hout = agent ? ah_out : nh_out;

    const int lane = tid & 63, wv = tid >> 6;
    const int col = lane & 15, quad = lane >> 4;

    __shared__ __attribute__((aligned(16))) uint hb[2][16][HS];
    __shared__ __attribute__((aligned(16))) ushort_t xb[50][16][8];

    // A fragments: Whh rows, single RTN bf16, pre-scaled by log2e (2log2e for
    // the g gate). A row = g*64+16wv+col.
    bf16x8 Aw[4][2];
    #pragma unroll
    for (int g = 0; g < 4; ++g) {
        const float sc = (g == 2) ? LOG2E2 : LOG2E;
        #pragma unroll
        for (int kt = 0; kt < 2; ++kt) {
            const float* p = whh + (size_t)(g * 64 + 16 * wv + col) * 64 + kt * 32 + quad * 8;
            float4 v0 = *(const float4*)p;
            float4 v1 = *(const float4*)(p + 4);
            float vv[8] = { v0.x, v0.y, v0.z, v0.w, v1.x, v1.y, v1.z, v1.w };
            bf16x8 h8;
            #pragma unroll
            for (int j = 0; j < 8; ++j) h8[j] = (short)bf_rtn(vv[j] * sc);
            Aw[g][kt] = h8;
        }
    }

    // 3rd-tile A fragments (x + bias, pre-scaled): nonzero only on quad 0.
    bf16x8 Ax[4];
    #pragma unroll
    for (int g = 0; g < 4; ++g) {
        const float sc = (g == 2) ? LOG2E2 : LOG2E;
        bf16x8 a;
        #pragma unroll
        for (int j = 0; j < 8; ++j) a[j] = 0;
        if (quad == 0) {
            const int row = g * 64 + 16 * wv + col;
            float w0 = wih[2 * row] * sc, w1 = wih[2 * row + 1] * sc;
            float b  = (bih[row] + bhh[row]) * sc;
            ushort_t w0h = bf_hi(w0), w1h = bf_hi(w1);
            ushort_t bh  = bf_hi(b);
            a[0] = (short)w0h;
            a[1] = (short)w1h;
            a[2] = (short)bf_hi(w0 - bf_f(w0h));
            a[3] = (short)bf_hi(w1 - bf_f(w1h));
            a[4] = (short)w0h;
            a[5] = (short)w1h;
            a[6] = (short)bh;
            a[7] = (short)bf_hi(b - bf_f(bh));
        }
        Ax[g] = a;
    }

    for (int idx = tid; idx < 50 * 16; idx += 256) {
        const int t = idx >> 4, s = idx & 15;
        const float* xp = x + (size_t)(seq0 + s) * 100 + 2 * t;
        float x0 = xp[0], x1 = xp[1];
        ushort_t h0 = bf_hi(x0), h1 = bf_hi(x1);
        ushort_t* e = &xb[t][s][0];
        e[0] = h0; e[1] = h1;
        e[2] = h0; e[3] = h1;
        e[4] = bf_hi(x0 - bf_f(h0));
        e[5] = bf_hi(x1 - bf_f(h1));
        e[6] = 0x3F80; e[7] = 0x3F80;
    }
    for (int i = tid; i < 16 * HS; i += 256) (&hb[0][0][0])[i] = 0u;
    __syncthreads();

    float c[4] = {0.f, 0.f, 0.f, 0.f};
    float hv[4];
    bf16x8 Bx = *(const bf16x8*)&xb[0][col][0];   // prefetched x-tile, t=0

    for (int t = 0; t < 50; ++t) {
        const int cur = t & 1, nxt = cur ^ 1;

        const f32x4 z4 = {0.f, 0.f, 0.f, 0.f};
        f32x4 acc[4];
        #pragma unroll
        for (int g = 0; g < 4; ++g)
            acc[g] = __builtin_amdgcn_mfma_f32_16x16x32_bf16(Ax[g], Bx, z4, 0, 0, 0);

        // Whh @ h: 1 MFMA per gate per kt
        #pragma unroll
        for (int kt = 0; kt < 2; ++kt) {
            bf16x8 Bhi = *(const bf16x8*)&hb[cur][col][kt * 16 + quad * 4];
            #pragma unroll
            for (int g = 0; g < 4; ++g)
                acc[g] = __builtin_amdgcn_mfma_f32_16x16x32_bf16(Aw[g][kt], Bhi, acc[g], 0, 0, 0);
        }

        // cell update: lane owns seq=col, units 16wv + 4quad + r
        #pragma unroll
        for (int r = 0; r < 4; ++r)
            hv[r] = cell_update_p(acc[0][r], acc[1][r], acc[2][r], acc[3][r], c[r]);

        // pack h (packed RTN cvt) -> LDS
        {
            __hip_bfloat162 p01 = __float22bfloat162_rn(make_float2(hv[0], hv[1]));
            __hip_bfloat162 p23 = __float22bfloat162_rn(make_float2(hv[2], hv[3]));
            uint2 hi2;
            union { __hip_bfloat162 b; uint u; } c0, c1;
            c0.b = p01; c1.b = p23;
            hi2.x = c0.u;
            hi2.y = c1.u;
            const int di = 8 * wv + 2 * quad;
            *(uint2*)&hb[nxt][col][di] = hi2;
        }
        // prefetch next x-tile BEFORE the barrier (xb is read-only: safe)
        if (t < 49) Bx = *(const bf16x8*)&xb[t + 1][col][0];
        __syncthreads();
    }

    // peeled final store (hv holds t=49 values)
    {
        float4 o4 = make_float4(hv[0], hv[1], hv[2], hv[3]);
        *(float4*)(hout + (size_t)(seq0 + col) * 64 + 16 * wv + 4 * quad) = o4;
    }
}

// ================= decoder R21: MFMA recurrence, enc-clone =================
// 32 blocks x 512 thr (8 waves); 16 seqs/block. Wave wv owns j in
// [16wv,16wv+16) for all 4 gates: 4 gate-tiles x kt=4 (K=128) = 16 MFMA/step.
// Lane (col=lane&15, quad=lane>>4) owns seq=col, j = 16wv + 4quad + r.
// hb2: bf16 h for recurrence (68-dword pad); hsf: fp32 h for pred epilogue
// (136-float pad), double-buffered so wave7's pred(t) can't race t+1's pack.
#define DHS 68
#define FHS 136

__global__ __launch_bounds__(512) void dec21_kernel(
    const float* __restrict__ ah, const float* __restrict__ nh,
    const float* __restrict__ d_wih, const float* __restrict__ d_whh,
    const float* __restrict__ d_bih, const float* __restrict__ d_bhh,
    const float* __restrict__ e_w, const float* __restrict__ e_b,
    float* __restrict__ out)
{
    const int tid = threadIdx.x, blk = blockIdx.x;
    const int lane = tid & 63, wv = tid >> 6;
    const int col = lane & 15, quad = lane >> 4;
    const int seqg0 = blk * 16;

    __shared__ __attribute__((aligned(16))) uint  hb2[2][16][DHS];
    __shared__ __attribute__((aligned(16))) float hsf[2][16][FHS];
    __shared__ float ews[2][128];
    __shared__ float ebs[2];

    // W = (d_wih + d_whh), bf16 RTN, log2e-prescaled. A row = g*128+16wv+col,
    // k-elems kt*32 + quad*8 .. +7, kt=0..3.
    bf16x8 Aw[4][4];
    #pragma unroll
    for (int g = 0; g < 4; ++g) {
        const float sc = (g == 2) ? LOG2E2 : LOG2E;
        const size_t rowb = (size_t)(g * 128 + 16 * wv + col) * 128;
        #pragma unroll
        for (int kt = 0; kt < 4; ++kt) {
            const float* pa = d_wih + rowb + kt * 32 + quad * 8;
            const float* pb = d_whh + rowb + kt * 32 + quad * 8;
            float4 a0 = *(const float4*)pa, a1 = *(const float4*)(pa + 4);
            float4 b0 = *(const float4*)pb, b1 = *(const float4*)(pb + 4);
            float vv[8] = { a0.x + b0.x, a0.y + b0.y, a0.z + b0.z, a0.w + b0.w,
                            a1.x + b1.x, a1.y + b1.y, a1.z + b1.z, a1.w + b1.w };
            bf16x8 h8;
            #pragma unroll
            for (int j = 0; j < 8; ++j) h8[j] = (short)bf_rtn(vv[j] * sc);
            Aw[g][kt] = h8;
        }
    }
    // Bias (pre-scaled), per lane's (quad, r): row = g*128 + 16wv + 4quad + r.
    float bias_[4][4];
    #pragma unroll
    for (int g = 0; g < 4; ++g) {
        const float sc = (g == 2) ? LOG2E2 : LOG2E;
        #pragma unroll
        for (int r = 0; r < 4; ++r) {
            const int row = g * 128 + 16 * wv + 4 * quad + r;
            bias_[g][r] = (d_bih[row] + d_bhh[row]) * sc;
        }
    }

    // h0 = [agent_emb | mean(neigh_emb)]: fp32 into hsf[0], bf16 into hb2[0].
    for (int idx = tid; idx < 16 * 128; idx += 512) {
        const int seq = idx >> 7, j = idx & 127;
        const int gseq = seqg0 + seq;
        float v;
        if (j < 64) {
            v = ah[(size_t)gseq * 64 + j];
        } else {
            float acc = 0.f;
            for (int n = 0; n < 32; ++n)
                acc += nh[(size_t)(gseq * 32 + n) * 64 + (j - 64)];
            v = acc * (1.0f / 32.0f);
        }
        hsf[0][seq][j] = v;
        ((ushort_t*)&hb2[0][seq][0])[j] = bf_rtn(v);
    }
    if (tid < 256) ews[tid >> 7][tid & 127] = e_w[tid];
    if (tid < 2) ebs[tid] = e_b[tid];
    __syncthreads();

    float c[4] = {0.f, 0.f, 0.f, 0.f};
    int cur = 0;
    for (int t = 0; t < 30; ++t) {
        const int nxt = cur ^ 1;

        // B fragments shared across the 4 gate-tiles
        bf16x8 Bh0 = *(const bf16x8*)&hb2[cur][col][0 * 16 + quad * 4];
        bf16x8 Bh1 = *(const bf16x8*)&hb2[cur][col][1 * 16 + quad * 4];
        bf16x8 Bh2 = *(const bf16x8*)&hb2[cur][col][2 * 16 + quad * 4];
        bf16x8 Bh3 = *(const bf16x8*)&hb2[cur][col][3 * 16 + quad * 4];

        const f32x4 z4 = {0.f, 0.f, 0.f, 0.f};
        f32x4 acc[4];
        #pragma unroll
        for (int g = 0; g < 4; ++g) {
            f32x4 a = __builtin_amdgcn_mfma_f32_16x16x32_bf16(Aw[g][0], Bh0, z4, 0, 0, 0);
            a = __builtin_amdgcn_mfma_f32_16x16x32_bf16(Aw[g][1], Bh1, a, 0, 0, 0);
            a = __builtin_amdgcn_mfma_f32_16x16x32_bf16(Aw[g][2], Bh2, a, 0, 0, 0);
            a = __builtin_amdgcn_mfma_f32_16x16x32_bf16(Aw[g][3], Bh3, a, 0, 0, 0);
            acc[g] = a;
        }

        float hv[4];
        #pragma unroll
        for (int r = 0; r < 4; ++r)
            hv[r] = cell_update_p(acc[0][r] + bias_[0][r], acc[1][r] + bias_[1][r],
                                  acc[2][r] + bias_[2][r], acc[3][r] + bias_[3][r], c[r]);

        // pack h: bf16 (recurrence) + fp32 (pred epilogue)
        {
            union { __hip_bfloat162 b; uint u; } q0, q1;
            q0.b = __float22bfloat162_rn(make_float2(hv[0], hv[1]));
            q1.b = __float22bfloat162_rn(make_float2(hv[2], hv[3]));
            uint2 hi2; hi2.x = q0.u; hi2.y = q1.u;
            *(uint2*)&hb2[nxt][col][8 * wv + 2 * quad] = hi2;
            *(float4*)&hsf[nxt][col][16 * wv + 4 * quad] =
                make_float4(hv[0], hv[1], hv[2], hv[3]);
        }
        __syncthreads();

        // pred(t) on wave 7 (overlaps other waves' next-step MFMAs).
        // hsf is double-buffered: t+1 writes hsf[cur], we read hsf[nxt]; and
        // t+2's write to hsf[nxt] is after barrier(t+1) which we gate. Safe.
        if (wv == 7) {
            const int pr = lane >> 1, half = lane & 1;
            const int seq = pr >> 1, o = pr & 1;
            const float4* hp = (const float4*)&hsf[nxt][seq][half * 64];
            const float4* wp = (const float4*)&ews[o][half * 64];
            float a0 = 0.f, a1 = 0.f, a2 = 0.f, a3 = 0.f;
            #pragma unroll
            for (int k = 0; k < 16; ++k) {
                float4 h4 = hp[k], w4 = wp[k];
                a0 = __builtin_fmaf(h4.x, w4.x, a0);
                a1 = __builtin_fmaf(h4.y, w4.y, a1);
                a2 = __builtin_fmaf(h4.z, w4.z, a2);
                a3 = __builtin_fmaf(h4.w, w4.w, a3);
            }
            float p = (a0 + a1) + (a2 + a3);
            p += __shfl_xor(p, 1);
            if (half == 0)
                out[((size_t)(seqg0 + seq) * 30 + t) * 2 + o] = p + ebs[o];
        }
        cur = nxt;
    }
}

extern "C" void kernel_launch(void* const* d_in, const int* in_sizes, int n_in,
                              void* d_out, int out_size, void* d_ws, size_t ws_size,
                              hipStream_t stream)
{
    const float* agent_traj = (const float*)d_in[0];
    const float* neigh_traj = (const float*)d_in[1];
    const float* a_wih = (const float*)d_in[2];
    const float* a_whh = (const float*)d_in[3];
    const float* a_bih = (const float*)d_in[4];
    const float* a_bhh = (const float*)d_in[5];
    const float* n_wih = (const float*)d_in[6];
    const float* n_whh = (const float*)d_in[7];
    const float* n_bih = (const float*)d_in[8];
    const float* n_bhh = (const float*)d_in[9];
    const float* d_wih = (const float*)d_in[10];
    const float* d_whh = (const float*)d_in[11];
    const float* d_bih = (const float*)d_in[12];
    const float* d_bhh = (const float*)d_in[13];
    const float* e_w   = (const float*)d_in[14];
    const float* e_b   = (const float*)d_in[15];
    float* out = (float*)d_out;

    float* nh_ws = (float*)d_ws;            // 16384*64 fp32
    float* ah_ws = nh_ws + 16384 * 64;      // 512*64 fp32

    enc21_kernel<<<dim3(1024 + 32), dim3(256), 0, stream>>>(
        agent_traj, neigh_traj,
        a_wih, a_whh, a_bih, a_bhh,
        n_wih, n_whh, n_bih, n_bhh,
        nh_ws, ah_ws);

    dec21_kernel<<<dim3(32), dim3(512), 0, stream>>>(
        ah_ws, nh_ws, d_wih, d_whh, d_bih, d_bhh, e_w, e_b, out);
}